// Round 6
// baseline (205.701 us; speedup 1.0000x reference)
//
#include <hip/hip_runtime.h>
#include <hip/hip_bf16.h>

// M=2048, A=64, E=128, H=256, bond types=4, atom types=118
typedef __bf16 bf16x8 __attribute__((ext_vector_type(8)));
typedef float f32x16 __attribute__((ext_vector_type(16)));

__device__ inline unsigned short f2bf(float f) {
  __hip_bfloat16 h = __float2bfloat16(f);
  return *reinterpret_cast<unsigned short*>(&h);
}
__device__ inline unsigned pack2bf(float a, float b) {
  return (unsigned)f2bf(a) | ((unsigned)f2bf(b) << 16);
}
__device__ inline uint2 pack4bf(float a, float b, float c, float d) {
  uint2 r; r.x = pack2bf(a, b); r.y = pack2bf(c, d); return r;
}
__device__ inline bf16x8 as_bf16x8(uint4 v) { return __builtin_bit_cast(bf16x8, v); }
__device__ inline float bitf(unsigned u) { return __builtin_bit_cast(float, u); }
__device__ inline f32x16 mfma16(bf16x8 a, bf16x8 b, f32x16 c) {
  return __builtin_amdgcn_mfma_f32_32x32x16_bf16(a, b, c, 0, 0, 0);
}

// LDS addr of X/h element: row (R*32+l31), k-chunk KK, half h; XOR row-swizzle.
#define BADDR(XB, R, KK)                                                       \
  ((XB) + (((((R) * 32 + l31) << 9) + ((KK) << 5) + (h << 4)) ^ swz))

// MERGED dual-output GEMM: one pass over B (64 rows of XB), two weight
// matrices -> u (W1) and v (W2) accs, 64 rows x 64 cols each.
// 8 MFMA per kk for 2 LDS B-reads; depth-1 pair ping-pong; unroll disabled
// (full unroll -> load hoisting -> VGPR spill, r2-r4 lesson).
#define GEMMM(XB, W1PTR, W2PTR, CW_)                                           \
  {                                                                            \
    const unsigned char* w1_ = (const unsigned char*)(W1PTR) +                 \
                               (((CW_) + l31) << 5) + (h << 4);                \
    const unsigned char* w2_ = (const unsigned char*)(W2PTR) +                 \
                               (((CW_) + l31) << 5) + (h << 4);                \
    u00 = zero; u01 = zero; u10 = zero; u11 = zero;                            \
    v00 = zero; v01 = zero; v10 = zero; v11 = zero;                            \
    bf16x8 pB0 = *(const bf16x8*)BADDR(XB, 0, 0);                              \
    bf16x8 pB1 = *(const bf16x8*)BADDR(XB, 1, 0);                              \
    uint4 pA0 = *(const uint4*)(w1_ + 0);                                      \
    uint4 pA1 = *(const uint4*)(w1_ + 1024);                                   \
    uint4 pC0 = *(const uint4*)(w2_ + 0);                                      \
    uint4 pC1 = *(const uint4*)(w2_ + 1024);                                   \
    _Pragma("clang loop unroll(disable)")                                      \
    for (int kk = 0; kk < 16; kk += 2) {                                       \
      bf16x8 qB0 = *(const bf16x8*)BADDR(XB, 0, kk + 1);                       \
      bf16x8 qB1 = *(const bf16x8*)BADDR(XB, 1, kk + 1);                       \
      uint4 qA0 = *(const uint4*)(w1_ + ((kk + 1) << 13));                     \
      uint4 qA1 = *(const uint4*)(w1_ + ((kk + 1) << 13) + 1024);              \
      uint4 qC0 = *(const uint4*)(w2_ + ((kk + 1) << 13));                     \
      uint4 qC1 = *(const uint4*)(w2_ + ((kk + 1) << 13) + 1024);              \
      u00 = mfma16(as_bf16x8(pA0), pB0, u00);                                  \
      u10 = mfma16(as_bf16x8(pA1), pB0, u10);                                  \
      u01 = mfma16(as_bf16x8(pA0), pB1, u01);                                  \
      u11 = mfma16(as_bf16x8(pA1), pB1, u11);                                  \
      v00 = mfma16(as_bf16x8(pC0), pB0, v00);                                  \
      v10 = mfma16(as_bf16x8(pC1), pB0, v10);                                  \
      v01 = mfma16(as_bf16x8(pC0), pB1, v01);                                  \
      v11 = mfma16(as_bf16x8(pC1), pB1, v11);                                  \
      if (kk + 2 < 16) {                                                       \
        pB0 = *(const bf16x8*)BADDR(XB, 0, kk + 2);                            \
        pB1 = *(const bf16x8*)BADDR(XB, 1, kk + 2);                            \
        pA0 = *(const uint4*)(w1_ + ((kk + 2) << 13));                         \
        pA1 = *(const uint4*)(w1_ + ((kk + 2) << 13) + 1024);                  \
        pC0 = *(const uint4*)(w2_ + ((kk + 2) << 13));                         \
        pC1 = *(const uint4*)(w2_ + ((kk + 2) << 13) + 1024);                  \
      }                                                                        \
      u00 = mfma16(as_bf16x8(qA0), qB0, u00);                                  \
      u10 = mfma16(as_bf16x8(qA1), qB0, u10);                                  \
      u01 = mfma16(as_bf16x8(qA0), qB1, u01);                                  \
      u11 = mfma16(as_bf16x8(qA1), qB1, u11);                                  \
      v00 = mfma16(as_bf16x8(qC0), qB0, v00);                                  \
      v10 = mfma16(as_bf16x8(qC1), qB0, v10);                                  \
      v01 = mfma16(as_bf16x8(qC0), qB1, v01);                                  \
      v11 = mfma16(as_bf16x8(qC1), qB1, v11);                                  \
    }                                                                          \
  }

// write one 32x32 tile: rows (R*32+l31), cols (CW_+C*32..+31), bias+relu
#define WB22(DB, ACC, R, C, CW_, BIASPTR)                                      \
  _Pragma("unroll")                                                            \
  for (int g = 0; g < 4; ++g) {                                                \
    int xr_ = (R) * 32 + l31;                                                  \
    int col = (CW_) + (C) * 32 + g * 8 + h * 4;                                \
    float4 bb = *(const float4*)((BIASPTR) + col);                             \
    float v0 = fmaxf(ACC[4 * g + 0] + bb.x, 0.f);                              \
    float v1 = fmaxf(ACC[4 * g + 1] + bb.y, 0.f);                              \
    float v2 = fmaxf(ACC[4 * g + 2] + bb.z, 0.f);                              \
    float v3 = fmaxf(ACC[4 * g + 3] + bb.w, 0.f);                              \
    int off = ((xr_ << 9) + (col << 1)) ^ ((xr_ & 7) << 4);                    \
    *(uint2*)((DB) + off) = pack4bf(v0, v1, v2, v3);                           \
  }

#define WB22R(DB, ACC, R, C, CW_)                                              \
  _Pragma("unroll")                                                            \
  for (int g = 0; g < 4; ++g) {                                                \
    int xr_ = (R) * 32 + l31;                                                  \
    int col = (CW_) + (C) * 32 + g * 8 + h * 4;                                \
    int off = ((xr_ << 9) + (col << 1)) ^ ((xr_ & 7) << 4);                    \
    *(uint2*)((DB) + off) = pack4bf(ACC[4 * g + 0], ACC[4 * g + 1],            \
                                    ACC[4 * g + 2], ACC[4 * g + 3]);           \
  }

// f32 staging: 64x256 f32 -> bf16 LDS, row-swizzled
#define STAGE_X(DST, SRC)                                                      \
  _Pragma("unroll")                                                            \
  for (int it = 0; it < 8; ++it) {                                             \
    int lb = (it * 256 + tid) * 16;                                            \
    int d_ = lb ^ (((lb >> 9) & 7) << 4);                                      \
    const float4* s4 = (const float4*)((SRC) + (lb >> 1));                     \
    float4 f0 = s4[0], f1 = s4[1];                                             \
    uint4 v_ = { pack2bf(f0.x, f0.y), pack2bf(f0.z, f0.w),                     \
                 pack2bf(f1.x, f1.y), pack2bf(f1.z, f1.w) };                   \
    *(uint4*)((DST) + d_) = v_;                                                \
  }

// ---------------------------------------------------------------------------
// Pack Wp1 / Wa1 / Wa2 to bf16 fragment layout: ushort[(kk*N + n)*16 + dk]
// ---------------------------------------------------------------------------
__global__ __launch_bounds__(256) void k_pack(
    const float* __restrict__ wp1, const float* __restrict__ wa1,
    const float* __restrict__ wa2,
    unsigned short* __restrict__ dp1, unsigned short* __restrict__ da1,
    unsigned short* __restrict__ da2, float* __restrict__ accum)
{
  int b = blockIdx.x, tid = threadIdx.x;
  if (b == 0 && tid < 8) accum[tid] = 0.f;
  const float* src; unsigned short* dst; int e, logN, Nreal;
  if (b < 256)       { src = wp1; dst = dp1; e = b * 256 + tid;          logN = 8; Nreal = 256; }
  else if (b < 512)  { src = wa1; dst = da1; e = (b - 256) * 256 + tid;  logN = 8; Nreal = 256; }
  else               { src = wa2; dst = da2; e = (b - 512) * 256 + tid;  logN = 7; Nreal = 118; }
  int dk = e & 15;
  int rest = e >> 4;
  int n = rest & ((1 << logN) - 1);
  int kk = rest >> logN;
  int k = kk * 16 + dk;
  float v = (n < Nreal) ? src[k * Nreal + n] : 0.f;
  dst[e] = f2bf(v);
}

// ---------------------------------------------------------------------------
// Fold: Wct = Wp2 @ Wb1[0:256,:], Wcb = Wp2 @ Wb1[256:512,:]  (packed bf16)
//       bias_e = bp2 @ (Wb1t+Wb1b) + bb1
// ---------------------------------------------------------------------------
__global__ __launch_bounds__(256) void k_fold(
    const float* __restrict__ wp2, const float* __restrict__ wb1,
    const float* __restrict__ bp2, const float* __restrict__ bb1,
    unsigned short* __restrict__ dct, unsigned short* __restrict__ dcb,
    float* __restrict__ bias_e)
{
  int b = blockIdx.x, n = threadIdx.x;
  if (b < 512) {
    int k = b & 255;
    int off = (b < 256) ? 0 : 256;
    float s = 0.f;
    for (int t = 0; t < 256; ++t)
      s += wp2[k * 256 + t] * wb1[(t + off) * 256 + n];
    unsigned short* dst = (b < 256) ? dct : dcb;
    dst[((k >> 4) * 256 + n) * 16 + (k & 15)] = f2bf(s);
  } else {
    float s = bb1[n];
    for (int t = 0; t < 256; ++t)
      s += bp2[t] * (wb1[t * 256 + n] + wb1[(256 + t) * 256 + n]);
    bias_e[n] = s;
  }
}

// ---------------------------------------------------------------------------
// Fused per-molecule kernel, merged-GEMM version.
//  P1: {ha, h1} = X @ {Wa1, Wp1}  (one pass over X)
//  P2: atom logits = ha @ Wa2
//  P3: {hs, he} = h1 @ {Wct, Wcb} (one pass over h1)
// bufA: X -> h1 -> hs ;  bufB: ha -> logits(f32) -> he.
// ---------------------------------------------------------------------------
__global__ __launch_bounds__(256, 2) void k_mol(
    const float* __restrict__ node, const int* __restrict__ eidx,
    const int* __restrict__ btt, const int* __restrict__ att,
    const unsigned short* __restrict__ wp1p, const float* __restrict__ bp1,
    const unsigned short* __restrict__ wctp, const unsigned short* __restrict__ wcbp,
    const float* __restrict__ bias_e, const float* __restrict__ wb2,
    const float* __restrict__ bb2,
    const unsigned short* __restrict__ wa1p, const float* __restrict__ ba1,
    const unsigned short* __restrict__ wa2p, const float* __restrict__ ba2,
    float* __restrict__ accum)
{
  __shared__ __align__(16) unsigned char bufA[32768];
  __shared__ __align__(16) unsigned char bufB[32768];
  __shared__ float s_bias[256];
  __shared__ float4 s_wb2[256];
  __shared__ float s_b2a[128];
  __shared__ float s_red[8];
  const int tid = threadIdx.x;
  const int lane = tid & 63;
  const int w = tid >> 6;
  const int l31 = lane & 31;
  const int h = lane >> 5;
  const int swz = (l31 & 7) << 4;
  const int CW = w * 64;
  const int m = blockIdx.x;

  STAGE_X(bufA, node + (long)m * 16384);
  s_bias[tid] = bias_e[tid];
  s_wb2[tid] = ((const float4*)wb2)[tid];
  if (tid < 128) s_b2a[tid] = (tid < 118) ? ba2[tid] : 0.f;
  const int t_at = att[m * 64 + (tid >> 2)];
  __syncthreads();                 // b1: staging visible

  f32x16 zero = {};
  f32x16 u00, u01, u10, u11, v00, v01, v10, v11;

  // ===== P1: merged atom-L1 + bond-h1 (read X=bufA) =====
  GEMMM(bufA, wa1p, wp1p, CW);     // u = ha pre-act, v = h1 pre-act
  WB22(bufB, u00, 0, 0, CW, ba1);  // ha -> bufB (virgin buffer, no hazard)
  WB22(bufB, u10, 0, 1, CW, ba1);
  WB22(bufB, u01, 1, 0, CW, ba1);
  WB22(bufB, u11, 1, 1, CW, ba1);
  __syncthreads();                 // b2: all X reads done
  WB22(bufA, v00, 0, 0, CW, bp1);  // h1 over X
  WB22(bufA, v10, 0, 1, CW, bp1);
  WB22(bufA, v01, 1, 0, CW, bp1);
  WB22(bufA, v11, 1, 1, CW, bp1);
  __syncthreads();                 // b3: ha, h1 visible

  // ===== P2: atom layer 2: wave w -> cols w*32..+31 (128-pad), rows 0..63
  f32x16 accL0 = zero, accL1 = zero;
  {
    const int cw2 = w * 32;
    const unsigned char* wb_ = (const unsigned char*)wa2p +
                               ((cw2 + l31) << 5) + (h << 4);
    bf16x8 pB0 = *(const bf16x8*)BADDR(bufB, 0, 0);
    bf16x8 pB1 = *(const bf16x8*)BADDR(bufB, 1, 0);
    uint4 pA = *(const uint4*)(wb_);
    _Pragma("clang loop unroll(disable)")
    for (int kk = 0; kk < 16; kk += 2) {
      bf16x8 qB0 = *(const bf16x8*)BADDR(bufB, 0, kk + 1);
      bf16x8 qB1 = *(const bf16x8*)BADDR(bufB, 1, kk + 1);
      uint4 qA = *(const uint4*)(wb_ + ((kk + 1) << 12));
      accL0 = mfma16(as_bf16x8(pA), pB0, accL0);
      accL1 = mfma16(as_bf16x8(pA), pB1, accL1);
      if (kk + 2 < 16) {
        pB0 = *(const bf16x8*)BADDR(bufB, 0, kk + 2);
        pB1 = *(const bf16x8*)BADDR(bufB, 1, kk + 2);
        pA = *(const uint4*)(wb_ + ((kk + 2) << 12));
      }
      accL0 = mfma16(as_bf16x8(qA), qB0, accL0);
      accL1 = mfma16(as_bf16x8(qA), qB1, accL1);
    }
  }
  __syncthreads();                 // b4: all ha reads done; bufB reusable

  // logits (f32, +ba2) -> bufB, row-swizzled (row stride 512B)
  {
    const int cw2 = w * 32;
    #pragma unroll
    for (int q = 0; q < 16; ++q) {
      int col = cw2 + (q & 3) + 8 * (q >> 2) + 4 * h;
      if (col < 118) {
        float bv = s_b2a[col];
        int r0 = l31, r1 = 32 + l31;
        *(float*)(bufB + ((r0 << 9) + (((col << 2)) ^ ((r0 & 7) << 4)))) = accL0[q] + bv;
        *(float*)(bufB + ((r1 << 9) + (((col << 2)) ^ ((r1 & 7) << 4)))) = accL1[q] + bv;
      }
    }
  }
  __syncthreads();                 // b5: logits visible

  // atom epilogue: 4 lanes per row, cols split 30/30/30/28
  {
    const int row = tid >> 2, g4 = tid & 3;
    const int t = t_at;
    const unsigned char* lr = bufB + (row << 9);
    const int rswz = (row & 7) << 4;
    const int c0 = g4 * 30;
    const int cend = (g4 == 3) ? 118 : c0 + 30;
    float mx = -3.0e38f; int am = 127;
    for (int c = c0; c < cend; ++c) {
      float v = *(const float*)(lr + (((c << 2)) ^ rswz));
      if (v > mx) { mx = v; am = c; }
    }
    float mo = __shfl_xor(mx, 1); int amo = __shfl_xor(am, 1);
    if (mo > mx || (mo == mx && amo < am)) { mx = mo; am = amo; }
    mo = __shfl_xor(mx, 2); amo = __shfl_xor(am, 2);
    if (mo > mx || (mo == mx && amo < am)) { mx = mo; am = amo; }
    float s = 0.f, vt = 0.f;
    for (int c = c0; c < cend; ++c) {
      float v = *(const float*)(lr + (((c << 2)) ^ rswz));
      s += __expf(v - mx);
      if (c == t) vt = v;
    }
    s += __shfl_xor(s, 1); s += __shfl_xor(s, 2);
    vt += __shfl_xor(vt, 1); vt += __shfl_xor(vt, 2);
    float ce = 0.f, cc = 0.f;
    if (g4 == 0) { ce = __logf(s) + mx - vt; cc = (am == t) ? 1.f : 0.f; }
    #pragma unroll
    for (int d = 1; d < 64; d <<= 1) { ce += __shfl_xor(ce, d); cc += __shfl_xor(cc, d); }
    if (lane == 0) { s_red[w * 2] = ce; s_red[w * 2 + 1] = cc; }
  }

  // ===== P3: merged hs + he (read h1=bufA) =====
  GEMMM(bufA, wctp, wcbp, CW);     // u = hs, v = he
  // edge metadata: issue now, drains during b6
  const int es = eidx[m * 256 + (tid >> 1)];
  const int ed = eidx[m * 256 + 128 + (tid >> 1)];
  const int etg = btt[m * 128 + (tid >> 1)];
  const float b20 = bb2[0], b21 = bb2[1], b22 = bb2[2], b23 = bb2[3];
  __syncthreads();                 // b6: h1 reads + epilogue done; s_red visible
  if (tid == 0) {
    atomicAdd(accum + 2, s_red[0] + s_red[2] + s_red[4] + s_red[6]);
    atomicAdd(accum + 3, s_red[1] + s_red[3] + s_red[5] + s_red[7]);
  }
  WB22R(bufA, u00, 0, 0, CW);      // hs over h1
  WB22R(bufA, u10, 0, 1, CW);
  WB22R(bufA, u01, 1, 0, CW);
  WB22R(bufA, u11, 1, 1, CW);
  WB22R(bufB, v00, 0, 0, CW);      // he over logits
  WB22R(bufB, v10, 0, 1, CW);
  WB22R(bufB, v01, 1, 0, CW);
  WB22R(bufB, v11, 1, 1, CW);
  __syncthreads();                 // b7: hs/he visible

  // edge phase: thread pair (2t,2t+1) -> edge t, col-halves. hs=bufA, he=bufB
  {
    const int hf = tid & 1;
    float lg0 = 0.f, lg1 = 0.f, lg2 = 0.f, lg3 = 0.f;
    #pragma unroll
    for (int j = 0; j < 16; ++j) {
      int c0 = hf * 128 + j * 8;
      int offS = ((es << 9) + (c0 << 1)) ^ ((es & 7) << 4);
      int offD = ((ed << 9) + (c0 << 1)) ^ ((ed & 7) << 4);
      uint4 us = *(const uint4*)(bufA + offS);
      uint4 ud = *(const uint4*)(bufB + offD);
      const unsigned* pu = (const unsigned*)&us;
      const unsigned* pv = (const unsigned*)&ud;
      #pragma unroll
      for (int q = 0; q < 4; ++q) {
        unsigned ua = pu[q], ub = pv[q];
        int c = c0 + 2 * q;
        float hlo = bitf(ua << 16) + bitf(ub << 16) + s_bias[c];
        float hhi = bitf(ua & 0xffff0000u) + bitf(ub & 0xffff0000u) + s_bias[c + 1];
        hlo = fmaxf(hlo, 0.f); hhi = fmaxf(hhi, 0.f);
        float4 w0 = s_wb2[c], w1 = s_wb2[c + 1];
        lg0 = fmaf(hlo, w0.x, fmaf(hhi, w1.x, lg0));
        lg1 = fmaf(hlo, w0.y, fmaf(hhi, w1.y, lg1));
        lg2 = fmaf(hlo, w0.z, fmaf(hhi, w1.z, lg2));
        lg3 = fmaf(hlo, w0.w, fmaf(hhi, w1.w, lg3));
      }
    }
    lg0 += __shfl_xor(lg0, 1); lg1 += __shfl_xor(lg1, 1);
    lg2 += __shfl_xor(lg2, 1); lg3 += __shfl_xor(lg3, 1);
    float ce = 0.f, cc = 0.f;
    if (hf == 0) {
      float l0 = lg0 + b20, l1 = lg1 + b21, l2 = lg2 + b22, l3 = lg3 + b23;
      int t = etg;
      int am = 0; float mx = l0;
      if (l1 > mx) { mx = l1; am = 1; }
      if (l2 > mx) { mx = l2; am = 2; }
      if (l3 > mx) { mx = l3; am = 3; }
      float s = __expf(l0 - mx) + __expf(l1 - mx) + __expf(l2 - mx) + __expf(l3 - mx);
      float lt = (t == 0) ? l0 : (t == 1) ? l1 : (t == 2) ? l2 : l3;
      ce = __logf(s) + mx - lt;
      cc = (am == t) ? 1.f : 0.f;
    }
    #pragma unroll
    for (int d = 1; d < 64; d <<= 1) { ce += __shfl_xor(ce, d); cc += __shfl_xor(cc, d); }
    if (lane == 0) { s_red[w * 2] = ce; s_red[w * 2 + 1] = cc; }
    __syncthreads();
    if (tid == 0) {
      atomicAdd(accum + 0, s_red[0] + s_red[2] + s_red[4] + s_red[6]);
      atomicAdd(accum + 1, s_red[1] + s_red[3] + s_red[5] + s_red[7]);
    }
  }
}

__global__ __launch_bounds__(64) void k_final(const float* __restrict__ accum,
                                              float* __restrict__ out)
{
  if (threadIdx.x == 0) {
    float bce = accum[0] / 262144.f;
    float bcc = accum[1] / 262144.f;
    float ace = accum[2] / 131072.f;
    float acc_ = accum[3] / 131072.f;
    out[0] = 0.5f * bce + 0.5f * ace;
    out[1] = bcc;
    out[2] = acc_;
  }
}

extern "C" void kernel_launch(void* const* d_in, const int* in_sizes, int n_in,
                              void* d_out, int out_size, void* d_ws, size_t ws_size,
                              hipStream_t stream)
{
  const float* node = (const float*)d_in[0];
  const int* eidx   = (const int*)d_in[1];
  const int* btt    = (const int*)d_in[2];
  const int* att    = (const int*)d_in[3];
  const float* Wp1 = (const float*)d_in[4];
  const float* bp1 = (const float*)d_in[5];
  const float* Wp2 = (const float*)d_in[6];
  const float* bp2 = (const float*)d_in[7];
  const float* Wb1 = (const float*)d_in[8];
  const float* bb1 = (const float*)d_in[9];
  const float* Wb2 = (const float*)d_in[10];
  const float* bb2 = (const float*)d_in[11];
  const float* Wa1 = (const float*)d_in[12];
  const float* ba1 = (const float*)d_in[13];
  const float* Wa2 = (const float*)d_in[14];
  const float* ba2 = (const float*)d_in[15];

  char* ws = (char*)d_ws;
  float* accum = (float*)ws;
  unsigned short* dp1 = (unsigned short*)(ws + 256);
  unsigned short* da1 = (unsigned short*)(ws + 131328);
  unsigned short* da2 = (unsigned short*)(ws + 262400);
  unsigned short* dct = (unsigned short*)(ws + 327936);
  unsigned short* dcb = (unsigned short*)(ws + 459008);
  float* bias_e       = (float*)(ws + 590080);

  k_pack<<<640, 256, 0, stream>>>(Wp1, Wa1, Wa2, dp1, da1, da2, accum);
  k_fold<<<513, 256, 0, stream>>>(Wp2, Wb1, bp2, bb1, dct, dcb, bias_e);
  k_mol<<<2048, 256, 0, stream>>>(node, eidx, btt, att, dp1, bp1, dct, dcb,
                                  bias_e, Wb2, bb2, da1, ba1, da2, ba2, accum);
  k_final<<<1, 64, 0, stream>>>(accum, (float*)d_out);
}

// Round 7
// 188.455 us; speedup vs baseline: 1.0915x; 1.0915x over previous
//
#include <hip/hip_runtime.h>
#include <hip/hip_bf16.h>

// M=2048, A=64, E=128, H=256, bond types=4, atom types=118
typedef __bf16 bf16x8 __attribute__((ext_vector_type(8)));
typedef float f32x16 __attribute__((ext_vector_type(16)));

__device__ inline unsigned short f2bf(float f) {
  __hip_bfloat16 h = __float2bfloat16(f);
  return *reinterpret_cast<unsigned short*>(&h);
}
__device__ inline unsigned pack2bf(float a, float b) {
  return (unsigned)f2bf(a) | ((unsigned)f2bf(b) << 16);
}
__device__ inline uint2 pack4bf(float a, float b, float c, float d) {
  uint2 r; r.x = pack2bf(a, b); r.y = pack2bf(c, d); return r;
}
__device__ inline bf16x8 as_bf16x8(uint4 v) { return __builtin_bit_cast(bf16x8, v); }
__device__ inline float bitf(unsigned u) { return __builtin_bit_cast(float, u); }
__device__ inline f32x16 mfma16(bf16x8 a, bf16x8 b, f32x16 c) {
  return __builtin_amdgcn_mfma_f32_32x32x16_bf16(a, b, c, 0, 0, 0);
}

// LDS addr of X/h element: row (rw+l31), k-chunk KK, half h; XOR row-swizzle.
#define BROW(XB, KK)                                                           \
  ((XB) + ((((rw + l31) << 9) + ((KK) << 5) + (h << 4)) ^ swz))

// 8-wave merged dual-output GEMM: wave = 32 rows (rw) x 64 cols (cw) of BOTH
// W1 -> u0,u1 and W2 -> v0,v1. 4 MFMA + 1 LDS-B + 4 A-loads per kk.
// Depth-1 ping-pong; K-loop unrolling disabled (unroll -> hoist -> spill).
#define GEMM8(XB, W1PTR, W2PTR)                                                \
  {                                                                            \
    const unsigned char* w1_ = (const unsigned char*)(W1PTR) +                 \
                               ((cw + l31) << 5) + (h << 4);                   \
    const unsigned char* w2_ = (const unsigned char*)(W2PTR) +                 \
                               ((cw + l31) << 5) + (h << 4);                   \
    u0 = zero; u1 = zero; v0 = zero; v1 = zero;                                \
    bf16x8 pB = *(const bf16x8*)BROW(XB, 0);                                   \
    uint4 pA0 = *(const uint4*)(w1_);                                          \
    uint4 pA1 = *(const uint4*)(w1_ + 1024);                                   \
    uint4 pC0 = *(const uint4*)(w2_);                                          \
    uint4 pC1 = *(const uint4*)(w2_ + 1024);                                   \
    _Pragma("clang loop unroll(disable)")                                      \
    for (int kk = 0; kk < 16; kk += 2) {                                       \
      bf16x8 qB = *(const bf16x8*)BROW(XB, kk + 1);                            \
      uint4 qA0 = *(const uint4*)(w1_ + ((kk + 1) << 13));                     \
      uint4 qA1 = *(const uint4*)(w1_ + ((kk + 1) << 13) + 1024);              \
      uint4 qC0 = *(const uint4*)(w2_ + ((kk + 1) << 13));                     \
      uint4 qC1 = *(const uint4*)(w2_ + ((kk + 1) << 13) + 1024);              \
      u0 = mfma16(as_bf16x8(pA0), pB, u0);                                     \
      u1 = mfma16(as_bf16x8(pA1), pB, u1);                                     \
      v0 = mfma16(as_bf16x8(pC0), pB, v0);                                     \
      v1 = mfma16(as_bf16x8(pC1), pB, v1);                                     \
      if (kk + 2 < 16) {                                                       \
        pB = *(const bf16x8*)BROW(XB, kk + 2);                                 \
        pA0 = *(const uint4*)(w1_ + ((kk + 2) << 13));                         \
        pA1 = *(const uint4*)(w1_ + ((kk + 2) << 13) + 1024);                  \
        pC0 = *(const uint4*)(w2_ + ((kk + 2) << 13));                         \
        pC1 = *(const uint4*)(w2_ + ((kk + 2) << 13) + 1024);                  \
      }                                                                        \
      u0 = mfma16(as_bf16x8(qA0), qB, u0);                                     \
      u1 = mfma16(as_bf16x8(qA1), qB, u1);                                     \
      v0 = mfma16(as_bf16x8(qC0), qB, v0);                                     \
      v1 = mfma16(as_bf16x8(qC1), qB, v1);                                     \
    }                                                                          \
  }

// write one 32x32 tile: rows rw+l31, cols cw + C*32..+31, bias+relu / raw
#define WB8(DB, ACC, C, BIASPTR)                                               \
  _Pragma("unroll")                                                            \
  for (int g = 0; g < 4; ++g) {                                                \
    int xr_ = rw + l31;                                                        \
    int col = cw + (C) * 32 + g * 8 + h * 4;                                   \
    float4 bb = *(const float4*)((BIASPTR) + col);                             \
    float v0_ = fmaxf(ACC[4 * g + 0] + bb.x, 0.f);                             \
    float v1_ = fmaxf(ACC[4 * g + 1] + bb.y, 0.f);                             \
    float v2_ = fmaxf(ACC[4 * g + 2] + bb.z, 0.f);                             \
    float v3_ = fmaxf(ACC[4 * g + 3] + bb.w, 0.f);                             \
    int off = ((xr_ << 9) + (col << 1)) ^ ((xr_ & 7) << 4);                    \
    *(uint2*)((DB) + off) = pack4bf(v0_, v1_, v2_, v3_);                       \
  }

#define WB8R(DB, ACC, C)                                                       \
  _Pragma("unroll")                                                            \
  for (int g = 0; g < 4; ++g) {                                                \
    int xr_ = rw + l31;                                                        \
    int col = cw + (C) * 32 + g * 8 + h * 4;                                   \
    int off = ((xr_ << 9) + (col << 1)) ^ ((xr_ & 7) << 4);                    \
    *(uint2*)((DB) + off) = pack4bf(ACC[4 * g + 0], ACC[4 * g + 1],            \
                                    ACC[4 * g + 2], ACC[4 * g + 3]);           \
  }

// f32 staging: 64x256 f32 -> bf16 LDS, row-swizzled (4 iters of 512 threads)
#define STAGE_X(DST, SRC)                                                      \
  _Pragma("unroll")                                                            \
  for (int it = 0; it < 4; ++it) {                                             \
    int lb = (it * 512 + tid) * 16;                                            \
    int d_ = lb ^ (((lb >> 9) & 7) << 4);                                      \
    const float4* s4 = (const float4*)((SRC) + (lb >> 1));                     \
    float4 f0 = s4[0], f1 = s4[1];                                             \
    uint4 v_ = { pack2bf(f0.x, f0.y), pack2bf(f0.z, f0.w),                     \
                 pack2bf(f1.x, f1.y), pack2bf(f1.z, f1.w) };                   \
    *(uint4*)((DST) + d_) = v_;                                                \
  }

// ---------------------------------------------------------------------------
// Pack Wp1 / Wa1 / Wa2 to bf16 fragment layout: ushort[(kk*N + n)*16 + dk]
// ---------------------------------------------------------------------------
__global__ __launch_bounds__(256) void k_pack(
    const float* __restrict__ wp1, const float* __restrict__ wa1,
    const float* __restrict__ wa2,
    unsigned short* __restrict__ dp1, unsigned short* __restrict__ da1,
    unsigned short* __restrict__ da2, float* __restrict__ accum)
{
  int b = blockIdx.x, tid = threadIdx.x;
  if (b == 0 && tid < 8) accum[tid] = 0.f;
  const float* src; unsigned short* dst; int e, logN, Nreal;
  if (b < 256)       { src = wp1; dst = dp1; e = b * 256 + tid;          logN = 8; Nreal = 256; }
  else if (b < 512)  { src = wa1; dst = da1; e = (b - 256) * 256 + tid;  logN = 8; Nreal = 256; }
  else               { src = wa2; dst = da2; e = (b - 512) * 256 + tid;  logN = 7; Nreal = 118; }
  int dk = e & 15;
  int rest = e >> 4;
  int n = rest & ((1 << logN) - 1);
  int kk = rest >> logN;
  int k = kk * 16 + dk;
  float v = (n < Nreal) ? src[k * Nreal + n] : 0.f;
  dst[e] = f2bf(v);
}

// ---------------------------------------------------------------------------
// Fold: Wct = Wp2 @ Wb1[0:256,:], Wcb = Wp2 @ Wb1[256:512,:]  (packed bf16)
//       bias_e = bp2 @ (Wb1t+Wb1b) + bb1
// ---------------------------------------------------------------------------
__global__ __launch_bounds__(256) void k_fold(
    const float* __restrict__ wp2, const float* __restrict__ wb1,
    const float* __restrict__ bp2, const float* __restrict__ bb1,
    unsigned short* __restrict__ dct, unsigned short* __restrict__ dcb,
    float* __restrict__ bias_e)
{
  int b = blockIdx.x, n = threadIdx.x;
  if (b < 512) {
    int k = b & 255;
    int off = (b < 256) ? 0 : 256;
    float s = 0.f;
    for (int t = 0; t < 256; ++t)
      s += wp2[k * 256 + t] * wb1[(t + off) * 256 + n];
    unsigned short* dst = (b < 256) ? dct : dcb;
    dst[((k >> 4) * 256 + n) * 16 + (k & 15)] = f2bf(s);
  } else {
    float s = bb1[n];
    for (int t = 0; t < 256; ++t)
      s += bp2[t] * (wb1[t * 256 + n] + wb1[(256 + t) * 256 + n]);
    bias_e[n] = s;
  }
}

// ---------------------------------------------------------------------------
// Fused per-molecule kernel, 8 waves (512 threads).
//  P1: {ha, h1} = X @ {Wa1, Wp1}   P2: logits = ha @ Wa2
//  P3: {hs, he} = h1 @ {Wct, Wcb}  + atom/edge epilogues.
// bufA: X -> h1 -> hs ;  bufB: ha -> logits(f32) -> he.
// Wave w: rows rw=(w>>2)*32, cols cw=(w&3)*64 (GEMM8) / cw2=(w&3)*32 (P2).
// ---------------------------------------------------------------------------
__global__ __launch_bounds__(512, 4) void k_mol(
    const float* __restrict__ node, const int* __restrict__ eidx,
    const int* __restrict__ btt, const int* __restrict__ att,
    const unsigned short* __restrict__ wp1p, const float* __restrict__ bp1,
    const unsigned short* __restrict__ wctp, const unsigned short* __restrict__ wcbp,
    const float* __restrict__ bias_e, const float* __restrict__ wb2,
    const float* __restrict__ bb2,
    const unsigned short* __restrict__ wa1p, const float* __restrict__ ba1,
    const unsigned short* __restrict__ wa2p, const float* __restrict__ ba2,
    float* __restrict__ accum)
{
  __shared__ __align__(16) unsigned char bufA[32768];
  __shared__ __align__(16) unsigned char bufB[32768];
  __shared__ float s_bias[256];
  __shared__ float4 s_wb2[256];
  __shared__ float s_b2a[128];
  __shared__ float s_red[16];
  const int tid = threadIdx.x;
  const int lane = tid & 63;
  const int w = tid >> 6;
  const int l31 = lane & 31;
  const int h = lane >> 5;
  const int swz = (l31 & 7) << 4;
  const int rw = (w >> 2) * 32;
  const int cw = (w & 3) * 64;
  const int m = blockIdx.x;

  STAGE_X(bufA, node + (long)m * 16384);
  if (tid < 256) {
    s_bias[tid] = bias_e[tid];
    s_wb2[tid] = ((const float4*)wb2)[tid];
  }
  if (tid < 128) s_b2a[tid] = (tid < 118) ? ba2[tid] : 0.f;
  const int t_at = att[m * 64 + (tid >> 3)];
  __syncthreads();                 // b1: staging visible

  f32x16 zero = {};
  f32x16 u0, u1, v0, v1;

  // ===== P1: merged atom-L1 + bond-h1 (read X=bufA) =====
  GEMM8(bufA, wa1p, wp1p);         // u = ha pre-act, v = h1 pre-act
  WB8(bufB, u0, 0, ba1);           // ha -> bufB (virgin, no hazard)
  WB8(bufB, u1, 1, ba1);
  __syncthreads();                 // b2: all X reads done
  WB8(bufA, v0, 0, bp1);           // h1 over X
  WB8(bufA, v1, 1, bp1);
  __syncthreads();                 // b3: ha, h1 visible

  // ===== P2: atom layer 2: wave w -> rows rw, cols cw2=(w&3)*32 =====
  f32x16 aL = zero;
  {
    const int cw2 = (w & 3) * 32;
    const unsigned char* wb_ = (const unsigned char*)wa2p +
                               ((cw2 + l31) << 5) + (h << 4);
    bf16x8 pB = *(const bf16x8*)BROW(bufB, 0);
    uint4 pA = *(const uint4*)(wb_);
    _Pragma("clang loop unroll(disable)")
    for (int kk = 0; kk < 16; kk += 2) {
      bf16x8 qB = *(const bf16x8*)BROW(bufB, kk + 1);
      uint4 qA = *(const uint4*)(wb_ + ((kk + 1) << 12));
      aL = mfma16(as_bf16x8(pA), pB, aL);
      if (kk + 2 < 16) {
        pB = *(const bf16x8*)BROW(bufB, kk + 2);
        pA = *(const uint4*)(wb_ + ((kk + 2) << 12));
      }
      aL = mfma16(as_bf16x8(qA), qB, aL);
    }
  }
  __syncthreads();                 // b4: all ha reads done; bufB reusable

  // logits (f32, +ba2) -> bufB rows rw+l31, row-swizzled (row stride 512B)
  {
    const int cw2 = (w & 3) * 32;
    const int r0 = rw + l31;
    #pragma unroll
    for (int q = 0; q < 16; ++q) {
      int col = cw2 + (q & 3) + 8 * (q >> 2) + 4 * h;
      if (col < 118)
        *(float*)(bufB + ((r0 << 9) + (((col << 2)) ^ ((r0 & 7) << 4)))) =
            aL[q] + s_b2a[col];
    }
  }
  __syncthreads();                 // b5: logits visible

  // atom epilogue: 8 lanes per row, cols split 15x7 + 13
  {
    const int row = tid >> 3, g8 = tid & 7;
    const unsigned char* lr = bufB + (row << 9);
    const int rswz = (row & 7) << 4;
    const int c0 = g8 * 15;
    const int cend = (g8 == 7) ? 118 : c0 + 15;
    float mx = -3.0e38f; int am = 127;
    for (int c = c0; c < cend; ++c) {
      float v = *(const float*)(lr + (((c << 2)) ^ rswz));
      if (v > mx) { mx = v; am = c; }
    }
    #pragma unroll
    for (int d = 1; d < 8; d <<= 1) {
      float mo = __shfl_xor(mx, d); int amo = __shfl_xor(am, d);
      if (mo > mx || (mo == mx && amo < am)) { mx = mo; am = amo; }
    }
    float s = 0.f, vt = 0.f;
    for (int c = c0; c < cend; ++c) {
      float v = *(const float*)(lr + (((c << 2)) ^ rswz));
      s += __expf(v - mx);
      if (c == t_at) vt = v;
    }
    #pragma unroll
    for (int d = 1; d < 8; d <<= 1) { s += __shfl_xor(s, d); vt += __shfl_xor(vt, d); }
    float ce = 0.f, cc = 0.f;
    if (g8 == 0) { ce = __logf(s) + mx - vt; cc = (am == t_at) ? 1.f : 0.f; }
    #pragma unroll
    for (int d = 8; d < 64; d <<= 1) { ce += __shfl_xor(ce, d); cc += __shfl_xor(cc, d); }
    // lanes with g8==0 now all hold the wave sum contribution... reduce rest
    #pragma unroll
    for (int d = 1; d < 8; d <<= 1) { ce += __shfl_xor(ce, d); cc += __shfl_xor(cc, d); }
    if (lane == 0) { s_red[w * 2] = ce; s_red[w * 2 + 1] = cc; }
  }

  // ===== P3: merged hs + he (read h1=bufA) =====
  GEMM8(bufA, wctp, wcbp);         // u = hs, v = he
  const int es = eidx[m * 256 + (tid >> 2)];
  const int ed = eidx[m * 256 + 128 + (tid >> 2)];
  const int etg = btt[m * 128 + (tid >> 2)];
  const float b20 = bb2[0], b21 = bb2[1], b22 = bb2[2], b23 = bb2[3];
  __syncthreads();                 // b6: h1 reads + epilogue done
  if (tid == 0) {
    atomicAdd(accum + 2, s_red[0] + s_red[2] + s_red[4] + s_red[6] +
                         s_red[8] + s_red[10] + s_red[12] + s_red[14]);
    atomicAdd(accum + 3, s_red[1] + s_red[3] + s_red[5] + s_red[7] +
                         s_red[9] + s_red[11] + s_red[13] + s_red[15]);
  }
  WB8R(bufA, u0, 0);               // hs over h1
  WB8R(bufA, u1, 1);
  WB8R(bufB, v0, 0);               // he over logits
  WB8R(bufB, v1, 1);
  __syncthreads();                 // b7: hs/he visible

  // edge phase: 4 threads per edge (tid>>2), col quarter qf=tid&3
  {
    const int qf = tid & 3;
    float lg0 = 0.f, lg1 = 0.f, lg2 = 0.f, lg3 = 0.f;
    #pragma unroll
    for (int j = 0; j < 8; ++j) {
      int c0 = qf * 64 + j * 8;
      int offS = ((es << 9) + (c0 << 1)) ^ ((es & 7) << 4);
      int offD = ((ed << 9) + (c0 << 1)) ^ ((ed & 7) << 4);
      uint4 us = *(const uint4*)(bufA + offS);
      uint4 ud = *(const uint4*)(bufB + offD);
      const unsigned* pu = (const unsigned*)&us;
      const unsigned* pv = (const unsigned*)&ud;
      #pragma unroll
      for (int q = 0; q < 4; ++q) {
        unsigned ua = pu[q], ub = pv[q];
        int c = c0 + 2 * q;
        float hlo = bitf(ua << 16) + bitf(ub << 16) + s_bias[c];
        float hhi = bitf(ua & 0xffff0000u) + bitf(ub & 0xffff0000u) + s_bias[c + 1];
        hlo = fmaxf(hlo, 0.f); hhi = fmaxf(hhi, 0.f);
        float4 w0 = s_wb2[c], w1 = s_wb2[c + 1];
        lg0 = fmaf(hlo, w0.x, fmaf(hhi, w1.x, lg0));
        lg1 = fmaf(hlo, w0.y, fmaf(hhi, w1.y, lg1));
        lg2 = fmaf(hlo, w0.z, fmaf(hhi, w1.z, lg2));
        lg3 = fmaf(hlo, w0.w, fmaf(hhi, w1.w, lg3));
      }
    }
    lg0 += __shfl_xor(lg0, 1); lg1 += __shfl_xor(lg1, 1);
    lg2 += __shfl_xor(lg2, 1); lg3 += __shfl_xor(lg3, 1);
    lg0 += __shfl_xor(lg0, 2); lg1 += __shfl_xor(lg1, 2);
    lg2 += __shfl_xor(lg2, 2); lg3 += __shfl_xor(lg3, 2);
    float ce = 0.f, cc = 0.f;
    if (qf == 0) {
      float l0 = lg0 + b20, l1 = lg1 + b21, l2 = lg2 + b22, l3 = lg3 + b23;
      int t = etg;
      int am = 0; float mx = l0;
      if (l1 > mx) { mx = l1; am = 1; }
      if (l2 > mx) { mx = l2; am = 2; }
      if (l3 > mx) { mx = l3; am = 3; }
      float s = __expf(l0 - mx) + __expf(l1 - mx) + __expf(l2 - mx) + __expf(l3 - mx);
      float lt = (t == 0) ? l0 : (t == 1) ? l1 : (t == 2) ? l2 : l3;
      ce = __logf(s) + mx - lt;
      cc = (am == t) ? 1.f : 0.f;
    }
    #pragma unroll
    for (int d = 1; d < 64; d <<= 1) { ce += __shfl_xor(ce, d); cc += __shfl_xor(cc, d); }
    if (lane == 0) { s_red[w * 2] = ce; s_red[w * 2 + 1] = cc; }
    __syncthreads();
    if (tid == 0) {
      atomicAdd(accum + 0, s_red[0] + s_red[2] + s_red[4] + s_red[6] +
                           s_red[8] + s_red[10] + s_red[12] + s_red[14]);
      atomicAdd(accum + 1, s_red[1] + s_red[3] + s_red[5] + s_red[7] +
                           s_red[9] + s_red[11] + s_red[13] + s_red[15]);
    }
  }
}

__global__ __launch_bounds__(64) void k_final(const float* __restrict__ accum,
                                              float* __restrict__ out)
{
  if (threadIdx.x == 0) {
    float bce = accum[0] / 262144.f;
    float bcc = accum[1] / 262144.f;
    float ace = accum[2] / 131072.f;
    float acc_ = accum[3] / 131072.f;
    out[0] = 0.5f * bce + 0.5f * ace;
    out[1] = bcc;
    out[2] = acc_;
  }
}

extern "C" void kernel_launch(void* const* d_in, const int* in_sizes, int n_in,
                              void* d_out, int out_size, void* d_ws, size_t ws_size,
                              hipStream_t stream)
{
  const float* node = (const float*)d_in[0];
  const int* eidx   = (const int*)d_in[1];
  const int* btt    = (const int*)d_in[2];
  const int* att    = (const int*)d_in[3];
  const float* Wp1 = (const float*)d_in[4];
  const float* bp1 = (const float*)d_in[5];
  const float* Wp2 = (const float*)d_in[6];
  const float* bp2 = (const float*)d_in[7];
  const float* Wb1 = (const float*)d_in[8];
  const float* bb1 = (const float*)d_in[9];
  const float* Wb2 = (const float*)d_in[10];
  const float* bb2 = (const float*)d_in[11];
  const float* Wa1 = (const float*)d_in[12];
  const float* ba1 = (const float*)d_in[13];
  const float* Wa2 = (const float*)d_in[14];
  const float* ba2 = (const float*)d_in[15];

  char* ws = (char*)d_ws;
  float* accum = (float*)ws;
  unsigned short* dp1 = (unsigned short*)(ws + 256);
  unsigned short* da1 = (unsigned short*)(ws + 131328);
  unsigned short* da2 = (unsigned short*)(ws + 262400);
  unsigned short* dct = (unsigned short*)(ws + 327936);
  unsigned short* dcb = (unsigned short*)(ws + 459008);
  float* bias_e       = (float*)(ws + 590080);

  k_pack<<<640, 256, 0, stream>>>(Wp1, Wa1, Wa2, dp1, da1, da2, accum);
  k_fold<<<513, 256, 0, stream>>>(Wp2, Wb1, bp2, bb1, dct, dcb, bias_e);
  k_mol<<<2048, 512, 0, stream>>>(node, eidx, btt, att, dp1, bp1, dct, dcb,
                                  bias_e, Wb2, bb2, da1, ba1, da2, ba2, accum);
  k_final<<<1, 64, 0, stream>>>(accum, (float*)d_out);
}